// Round 2
// baseline (163.228 us; speedup 1.0000x reference)
//
#include <hip/hip_runtime.h>
#include <stdint.h>

// LePEAttention: B=4, C=64, H=W=128, NUM_HEADS=8, hd=8, H_sp=128, W_sp=2.
// All tensors fp32 (per reference). 512 blocks = (b, wi, channel-half),
// 256 threads = 4 waves = 4 heads. Lane owns rows n = 4*lane + r (r=0..3).

__global__ __launch_bounds__(256, 2)
void lepe_attn(const float* __restrict__ temp,
               const float* __restrict__ conv_w,
               const float* __restrict__ conv_b,
               float* __restrict__ out)
{
    // k_s: 32KB fp32 [256][32]; doubles as Q float2 staging ([128][32] float2),
    // and after the main loop is reused for conv weights (288) + bias (32).
    __shared__ __align__(16) float k_s[256 * 32];
    // v_s: 32KB fp32 [256][32], per-row quad swizzle: channel c of row n sits at
    // col ((c>>2 + (n>>2)) & 7)*4 + (c&3). Uniform (broadcast) reads in the main
    // loop are unaffected; per-lane epilogue reads drop from 64-way to ~8-way.
    __shared__ __align__(16) float v_s[256 * 32];

    const int tid  = threadIdx.x;
    const int bid  = blockIdx.x;
    const int h2   = bid & 1;          // channel half (heads h2*4 .. h2*4+3)
    const int wi   = (bid >> 1) & 63;  // window column index
    const int b    = bid >> 7;         // batch
    const int c0   = h2 * 32;          // first global channel of this block
    const int wave = tid >> 6;         // local head 0..3
    const int lane = tid & 63;

    const size_t cstr = 128 * 128;       // H*W
    const size_t sstr = 64 * cstr;       // C*H*W (q/k/v stride)
    const float* qg = temp + (size_t)b * 3 * sstr;
    const float* kg = qg + sstr;
    const float* vg = qg + 2 * sstr;

    const int cg  = tid & 31;   // channel-in-half for staging
    const int hh0 = tid >> 5;   // 0..7

    // ---- stage Q (float2 = both window columns of one image row) ----
    float2* q_s = (float2*)k_s;   // [128][32] float2
    {
        const size_t cb = (size_t)(c0 + cg) * cstr + (size_t)wi * 2;
        #pragma unroll
        for (int i = 0; i < 16; ++i) {
            int hh = i * 8 + hh0;
            q_s[hh * 32 + cg] = *(const float2*)(qg + cb + (size_t)hh * 128);
        }
    }
    __syncthreads();

    // ---- Q -> registers, folding scale * log2(e) ----
    float qr[4][8];
    {
        const float qs = 0.35355339059327373f * 1.4426950408889634f;
        #pragma unroll
        for (int hb = 0; hb < 2; ++hb) {
            int h = 2 * lane + hb;                    // image row 0..127
            const float2* p = &q_s[h * 32 + wave * 8];
            #pragma unroll
            for (int j = 0; j < 8; ++j) {
                float2 f = p[j];
                qr[2 * hb + 0][j] = f.x * qs;          // n even (w01=0)
                qr[2 * hb + 1][j] = f.y * qs;          // n odd  (w01=1)
            }
        }
    }
    __syncthreads();   // all Q reads done; safe to overwrite k_s

    // ---- stage K (plain fp32) and V (quad-swizzled fp32) ----
    {
        const size_t cb = (size_t)(c0 + cg) * cstr + (size_t)wi * 2;
        const int q_ = cg >> 2, j_ = cg & 3;
        #pragma unroll
        for (int i = 0; i < 16; ++i) {
            int hh = i * 8 + hh0;
            float2 fk = *(const float2*)(kg + cb + (size_t)hh * 128);
            float2 fv = *(const float2*)(vg + cb + (size_t)hh * 128);
            int n0 = 2 * hh, n1 = 2 * hh + 1;
            k_s[n0 * 32 + cg] = fk.x;
            k_s[n1 * 32 + cg] = fk.y;
            int sw = ((q_ + (hh >> 1)) & 7) * 4 + j_;   // n0>>2 == n1>>2 == hh>>1
            v_s[n0 * 32 + sw] = fv.x;
            v_s[n1 * 32 + sw] = fv.y;
        }
    }
    __syncthreads();

    // ---- attention main loop: softmax-without-max (safe in fp32 here) ----
    float acc[4][8], L[4];
    #pragma unroll
    for (int r = 0; r < 4; ++r) {
        L[r] = 0.f;
        #pragma unroll
        for (int d = 0; d < 8; ++d) acc[r][d] = 0.f;
    }

    #pragma unroll 4
    for (int m = 0; m < 256; ++m) {
        const float4 k0 = *(const float4*)&k_s[m * 32 + wave * 8];
        const float4 k1 = *(const float4*)&k_s[m * 32 + wave * 8 + 4];
        const int qq = m >> 2;
        const float4 v0 = *(const float4*)&v_s[m * 32 + ((2 * wave     + qq) & 7) * 4];
        const float4 v1 = *(const float4*)&v_s[m * 32 + ((2 * wave + 1 + qq) & 7) * 4];
        #pragma unroll
        for (int r = 0; r < 4; ++r) {
            float sa = fmaf(qr[r][3], k0.w, fmaf(qr[r][2], k0.z, fmaf(qr[r][1], k0.y, qr[r][0] * k0.x)));
            float sb = fmaf(qr[r][7], k1.w, fmaf(qr[r][6], k1.z, fmaf(qr[r][5], k1.y, qr[r][4] * k1.x)));
            float e = __builtin_amdgcn_exp2f(sa + sb);
            L[r] += e;
            acc[r][0] = fmaf(e, v0.x, acc[r][0]);
            acc[r][1] = fmaf(e, v0.y, acc[r][1]);
            acc[r][2] = fmaf(e, v0.z, acc[r][2]);
            acc[r][3] = fmaf(e, v0.w, acc[r][3]);
            acc[r][4] = fmaf(e, v1.x, acc[r][4]);
            acc[r][5] = fmaf(e, v1.y, acc[r][5]);
            acc[r][6] = fmaf(e, v1.z, acc[r][6]);
            acc[r][7] = fmaf(e, v1.w, acc[r][7]);
        }
    }
    __syncthreads();   // everyone done reading k_s

    // ---- stage depthwise-conv weights into k_s (reuse) ----
    float* wb = k_s;   // [0,288): w[c_local][dy][dx]; [288,320): bias
    for (int j = tid; j < 288; j += 256)
        wb[j] = conv_w[c0 * 9 + j];
    if (tid < 32) wb[288 + tid] = conv_b[c0 + tid];
    __syncthreads();

    // ---- gather V taps: rows 4*lane-2 .. 4*lane+5 (zero outside window) ----
    float tv[8][8];
    #pragma unroll
    for (int t = 0; t < 8; ++t) {
        int row = 4 * lane + t - 2;
        int rr = row < 0 ? 0 : (row > 255 ? 255 : row);
        int qq = rr >> 2;
        const float4 a = *(const float4*)&v_s[rr * 32 + ((2 * wave     + qq) & 7) * 4];
        const float4 c = *(const float4*)&v_s[rr * 32 + ((2 * wave + 1 + qq) & 7) * 4];
        float msk = (row >= 0 && row < 256) ? 1.f : 0.f;
        tv[t][0] = a.x * msk; tv[t][1] = a.y * msk; tv[t][2] = a.z * msk; tv[t][3] = a.w * msk;
        tv[t][4] = c.x * msk; tv[t][5] = c.y * msk; tv[t][6] = c.z * msk; tv[t][7] = c.w * msk;
    }

    // ---- epilogue: out = acc/L + depthwise conv (LePE), 32B stores ----
    const size_t obase = (size_t)b * 16384 * 64;
    #pragma unroll
    for (int r = 0; r < 4; ++r) {
        float rL = 1.0f / L[r];
        int hb = r >> 1, w01 = r & 1;
        float po8[8];
        #pragma unroll
        for (int d = 0; d < 8; ++d) {
            int cl = wave * 8 + d;
            float rp = wb[288 + cl];
            #pragma unroll
            for (int dy = 0; dy < 3; ++dy) {
                #pragma unroll
                for (int wp = 0; wp < 2; ++wp) {
                    int dx = wp + 1 - w01;                    // valid dx for this w01
                    rp = fmaf(wb[cl * 9 + dy * 3 + dx], tv[2 * hb + 2 * dy + wp][d], rp);
                }
            }
            po8[d] = fmaf(acc[r][d], rL, rp);
        }
        int h = 2 * lane + hb;
        size_t po = obase + ((size_t)h * 128 + wi * 2 + w01) * 64 + c0 + wave * 8;
        *(float4*)(out + po)     = make_float4(po8[0], po8[1], po8[2], po8[3]);
        *(float4*)(out + po + 4) = make_float4(po8[4], po8[5], po8[6], po8[7]);
    }
}

extern "C" void kernel_launch(void* const* d_in, const int* in_sizes, int n_in,
                              void* d_out, int out_size, void* d_ws, size_t ws_size,
                              hipStream_t stream) {
    const float* temp = (const float*)d_in[0];
    const float* cw   = (const float*)d_in[1];
    const float* cb   = (const float*)d_in[2];
    float* o = (float*)d_out;
    (void)in_sizes; (void)n_in; (void)out_size; (void)d_ws; (void)ws_size;
    lepe_attn<<<dim3(512), dim3(256), 0, stream>>>(temp, cw, cb, o);
}